// Round 6
// baseline (748.910 us; speedup 1.0000x reference)
//
#include <hip/hip_runtime.h>

// ---------------------------------------------------------------------------
// MultiHeadSelfAttention: B=4, L=2048, D=1024, H=16, dh=64.
// Established conventions (differential evidence, rounds 0-5):
//   inputs fp32, mask int32, d_out is FP32 storage (reference output dtype).
// Compute: fp32->bf16 staged MFMA 16x16x32, fp32 accumulation.
// ---------------------------------------------------------------------------

typedef __attribute__((ext_vector_type(8))) short short8;   // 8 bf16 = 4 VGPR
typedef __attribute__((ext_vector_type(4))) float f32x4;
typedef __attribute__((ext_vector_type(4))) float floatx4;

#define MFMA16(a, b, c) __builtin_amdgcn_mfma_f32_16x16x32_bf16((a), (b), (c), 0, 0, 0)

__device__ __forceinline__ short f2bf(float f) {
    unsigned u = __float_as_uint(f);
    u += 0x7FFF + ((u >> 16) & 1);   // round-to-nearest-even
    return (short)(u >> 16);
}

// ---------------------------------------------------------------------------
// GEMM: out = A(8192 x 1024) * W^T + bias. A, W, bias fp32; W is (N,K) row-
// major (torch Linear). 128x128 block tile, 4 waves each 64x64.
// layout 0 -> bf16 (B,H,L,dh); 1 -> bf16 (B,H,L,dh); 2 -> bf16 (B,H,dh,L);
// layout 3 -> fp32 plain (M,1024).
// ---------------------------------------------------------------------------
__global__ __launch_bounds__(256, 2) void gemm_kernel(
    const float* __restrict__ A, const float* __restrict__ W,
    const float* __restrict__ bias, void* __restrict__ out, int layout)
{
    __shared__ short As[128 * 40];   // stride 40 elems = 80B, 16B-aligned rows
    __shared__ short Bs[128 * 40];

    const int m0 = blockIdx.x * 128;
    const int n0 = blockIdx.y * 128;
    const int t = threadIdx.x;
    const int wave = t >> 6, lane = t & 63;
    const int wm = (wave >> 1) * 64, wn = (wave & 1) * 64;
    const int l15 = lane & 15, quad = lane >> 4;
    const int srow = t >> 2;          // 0..63
    const int scol = (t & 3) * 8;     // 0,8,16,24

    floatx4 acc[4][4];
#pragma unroll
    for (int i = 0; i < 4; i++)
#pragma unroll
        for (int j = 0; j < 4; j++) {
            acc[i][j][0] = 0.f; acc[i][j][1] = 0.f;
            acc[i][j][2] = 0.f; acc[i][j][3] = 0.f;
        }

    const size_t aoff0 = (size_t)(m0 + srow) * 1024 + scol;
    const size_t aoff1 = aoff0 + (size_t)64 * 1024;
    const size_t woff0 = (size_t)(n0 + srow) * 1024 + scol;
    const size_t woff1 = woff0 + (size_t)64 * 1024;

    for (int kb = 0; kb < 1024; kb += 32) {
        __syncthreads();
#pragma unroll
        for (int half = 0; half < 2; half++) {
            const float* p = A + (half ? aoff1 : aoff0) + kb;
            f32x4 u0 = *(const f32x4*)p;
            f32x4 u1 = *(const f32x4*)(p + 4);
            short8 s;
            s[0]=f2bf(u0[0]); s[1]=f2bf(u0[1]); s[2]=f2bf(u0[2]); s[3]=f2bf(u0[3]);
            s[4]=f2bf(u1[0]); s[5]=f2bf(u1[1]); s[6]=f2bf(u1[2]); s[7]=f2bf(u1[3]);
            *(short8*)&As[(srow + half * 64) * 40 + scol] = s;
        }
#pragma unroll
        for (int half = 0; half < 2; half++) {
            const float* p = W + (half ? woff1 : woff0) + kb;
            f32x4 u0 = *(const f32x4*)p;
            f32x4 u1 = *(const f32x4*)(p + 4);
            short8 s;
            s[0]=f2bf(u0[0]); s[1]=f2bf(u0[1]); s[2]=f2bf(u0[2]); s[3]=f2bf(u0[3]);
            s[4]=f2bf(u1[0]); s[5]=f2bf(u1[1]); s[6]=f2bf(u1[2]); s[7]=f2bf(u1[3]);
            *(short8*)&Bs[(srow + half * 64) * 40 + scol] = s;
        }
        __syncthreads();

        short8 af[4], bfr[4];
#pragma unroll
        for (int mi = 0; mi < 4; mi++)
            af[mi] = *(short8*)&As[(wm + mi * 16 + l15) * 40 + quad * 8];
#pragma unroll
        for (int ni = 0; ni < 4; ni++)
            bfr[ni] = *(short8*)&Bs[(wn + ni * 16 + l15) * 40 + quad * 8];
#pragma unroll
        for (int mi = 0; mi < 4; mi++)
#pragma unroll
            for (int ni = 0; ni < 4; ni++)
                acc[mi][ni] = MFMA16(af[mi], bfr[ni], acc[mi][ni]);
    }

    // Epilogue. C layout: col = lane&15, row = quad*4 + r.
#pragma unroll
    for (int ni = 0; ni < 4; ni++) {
        const int gn = n0 + wn + ni * 16 + l15;
        const float bv = bias[gn];
#pragma unroll
        for (int mi = 0; mi < 4; mi++) {
#pragma unroll
            for (int r = 0; r < 4; r++) {
                const int gm = m0 + wm + mi * 16 + quad * 4 + r;
                const float v = acc[mi][ni][r] + bv;
                if (layout == 3) {
                    ((float*)out)[(size_t)gm * 1024 + gn] = v;
                } else {
                    const int b = gm >> 11, l = gm & 2047;  // L = 2048
                    const int h = gn >> 6,  d = gn & 63;    // dh = 64
                    size_t idx;
                    if (layout == 2)
                        idx = ((size_t)(b * 16 + h) * 64 + d) * 2048 + l;
                    else
                        idx = ((size_t)(b * 16 + h) * 2048 + l) * 64 + d;
                    ((short*)out)[idx] = f2bf(v);
                }
            }
        }
    }
}

// ---------------------------------------------------------------------------
// Flash-style attention. Block = 4 waves, each wave owns 16 Q rows; iterates
// keys in chunks of 32 with online softmax. Q,K bf16 (B,H,L,dh); VT bf16
// (B,H,dh,L); mask int32 (B,L); O written FP32 as (B,L,D).
// ---------------------------------------------------------------------------
__global__ __launch_bounds__(256, 2) void attn_kernel(
    const short* __restrict__ Q, const short* __restrict__ Kc,
    const short* __restrict__ VT, const int* __restrict__ mask,
    float* __restrict__ O)
{
    __shared__ short Plds_all[4][16 * 32];   // per-wave P tile (16 x 32 keys)

    const int blk = blockIdx.x;
    const int qt = blk & 31;     // L/64 = 32 q-tiles
    const int bh = blk >> 5;     // 0..63
    const int b = bh >> 4, h = bh & 15;
    const int t = threadIdx.x;
    const int wave = t >> 6, lane = t & 63;
    const int l15 = lane & 15, quad = lane >> 4;
    short* Plds = Plds_all[wave];

    const short* Qb = Q  + (size_t)bh * 2048 * 64;
    const short* Kb = Kc + (size_t)bh * 2048 * 64;
    const short* Vb = VT + (size_t)bh * 64 * 2048;
    const int* mrow = mask + b * 2048;

    // Q fragments (A layout: m = lane&15, k = quad*8+j).
    const int qrow = qt * 64 + wave * 16 + l15;
    const short8 aq0 = *(const short8*)(Qb + (size_t)qrow * 64 + quad * 8);
    const short8 aq1 = *(const short8*)(Qb + (size_t)qrow * 64 + 32 + quad * 8);

    floatx4 accO[4];
#pragma unroll
    for (int ni = 0; ni < 4; ni++) {
        accO[ni][0] = 0.f; accO[ni][1] = 0.f; accO[ni][2] = 0.f; accO[ni][3] = 0.f;
    }
    float m_run[4] = {-1e30f, -1e30f, -1e30f, -1e30f};
    float l_run[4] = {0.f, 0.f, 0.f, 0.f};

    for (int c0 = 0; c0 < 2048; c0 += 32) {
        // --- S = Q K^T for 16 rows x 32 keys (two 16x16 C frags) ---
        const short* kp0 = Kb + (size_t)(c0 + l15) * 64 + quad * 8;
        const short* kp1 = kp0 + 16 * 64;
        const short8 bk00 = *(const short8*)(kp0);
        const short8 bk01 = *(const short8*)(kp0 + 32);
        const short8 bk10 = *(const short8*)(kp1);
        const short8 bk11 = *(const short8*)(kp1 + 32);

        floatx4 s0, s1;
        s0[0]=0.f; s0[1]=0.f; s0[2]=0.f; s0[3]=0.f;
        s1[0]=0.f; s1[1]=0.f; s1[2]=0.f; s1[3]=0.f;
        s0 = MFMA16(aq0, bk00, s0);
        s0 = MFMA16(aq1, bk01, s0);
        s1 = MFMA16(aq0, bk10, s1);
        s1 = MFMA16(aq1, bk11, s1);

        // --- scale + key-padding mask (ref: where(mask, -1e9, s/8)) ---
        const bool mk0 = (mrow[c0 + l15] != 0);
        const bool mk1 = (mrow[c0 + 16 + l15] != 0);
        float sv0[4], sv1[4], tmax[4];
#pragma unroll
        for (int r = 0; r < 4; r++) {
            sv0[r] = mk0 ? -1e9f : s0[r] * 0.125f;
            sv1[r] = mk1 ? -1e9f : s1[r] * 0.125f;
            tmax[r] = fmaxf(sv0[r], sv1[r]);
        }
#pragma unroll
        for (int r = 0; r < 4; r++) {
#pragma unroll
            for (int off = 1; off < 16; off <<= 1)
                tmax[r] = fmaxf(tmax[r], __shfl_xor(tmax[r], off));
        }

        float p0[4], p1[4];
#pragma unroll
        for (int r = 0; r < 4; r++) {
            const float mnew = fmaxf(m_run[r], tmax[r]);
            const float alpha = __expf(m_run[r] - mnew);
            p0[r] = __expf(sv0[r] - mnew);
            p1[r] = __expf(sv1[r] - mnew);
            float ts = p0[r] + p1[r];
#pragma unroll
            for (int off = 1; off < 16; off <<= 1)
                ts += __shfl_xor(ts, off);
            l_run[r] = l_run[r] * alpha + ts;
            m_run[r] = mnew;
            accO[0][r] *= alpha;
            accO[1][r] *= alpha;
            accO[2][r] *= alpha;
            accO[3][r] *= alpha;
        }

        // --- P: C layout -> A layout via per-wave LDS tile ---
#pragma unroll
        for (int r = 0; r < 4; r++) {
            Plds[(quad * 4 + r) * 32 + l15]      = f2bf(p0[r]);
            Plds[(quad * 4 + r) * 32 + 16 + l15] = f2bf(p1[r]);
        }
        asm volatile("s_waitcnt lgkmcnt(0)" ::: "memory");
        const short8 pa = *(short8*)&Plds[l15 * 32 + quad * 8];

        // --- O += P V  (B frag from VT: n = dh col, k = key, contiguous) ---
#pragma unroll
        for (int ni = 0; ni < 4; ni++) {
            const short8 bv = *(const short8*)(Vb + (size_t)(ni * 16 + l15) * 2048 + c0 + quad * 8);
            accO[ni] = MFMA16(pa, bv, accO[ni]);
        }
    }

    // Epilogue: O (B,L,D) FP32, divide by softmax denominator.
#pragma unroll
    for (int r = 0; r < 4; r++) {
        const float inv = 1.0f / fmaxf(l_run[r], 1e-30f);
        const int l = qt * 64 + wave * 16 + quad * 4 + r;
#pragma unroll
        for (int ni = 0; ni < 4; ni++) {
            O[(size_t)(b * 2048 + l) * 1024 + h * 64 + ni * 16 + l15] =
                accO[ni][r] * inv;
        }
    }
}

// ---------------------------------------------------------------------------
extern "C" void kernel_launch(void* const* d_in, const int* in_sizes, int n_in,
                              void* d_out, int out_size, void* d_ws, size_t ws_size,
                              hipStream_t stream)
{
    const float* x    = (const float*)d_in[0];
    const int*   mask = (const int*)d_in[1];
    const float* wq   = (const float*)d_in[2];
    const float* bq   = (const float*)d_in[3];
    const float* wk   = (const float*)d_in[4];
    const float* bk   = (const float*)d_in[5];
    const float* wv   = (const float*)d_in[6];
    const float* bv   = (const float*)d_in[7];
    const float* wo   = (const float*)d_in[8];
    const float* bo   = (const float*)d_in[9];
    float* out = (float*)d_out;   // FP32 output buffer (8M floats, 32 MB)

    // ws (48 MiB, proven-safe footprint):
    //   [Qbuf bf16 16MB][Kbuf bf16 16MB][Vt bf16 16MB]
    // Final fp32 GEMM result reuses Qbuf+Kbuf (32MB) after Q,K are dead.
    short* Qbuf = (short*)d_ws;
    short* Kbuf = Qbuf + (size_t)8 * 1024 * 1024;
    short* Vt   = Kbuf + (size_t)8 * 1024 * 1024;
    float* Fout = (float*)d_ws;   // 8M floats over Qbuf+Kbuf region

    dim3 grid(64, 8), block(256);
    gemm_kernel<<<grid, block, 0, stream>>>(x, wq, bq, Qbuf, 0);
    gemm_kernel<<<grid, block, 0, stream>>>(x, wk, bk, Kbuf, 1);
    gemm_kernel<<<grid, block, 0, stream>>>(x, wv, bv, Vt, 2);

    // Attention output (fp32, B,L,D) goes to d_out directly.
    attn_kernel<<<dim3(2048), block, 0, stream>>>(Qbuf, Kbuf, Vt, mask, out);

    // Final projection: A = d_out (fp32), result fp32 -> Fout (ws), then d2d.
    gemm_kernel<<<grid, block, 0, stream>>>(out, wo, bo, Fout, 3);

    hipMemcpyAsync(out, Fout, (size_t)out_size * sizeof(float),
                   hipMemcpyDeviceToDevice, stream);
}